// Round 7
// baseline (835.166 us; speedup 1.0000x reference)
//
#include <hip/hip_runtime.h>
#include <hip/hip_bf16.h>

typedef __attribute__((ext_vector_type(8))) short bf16x8;
typedef __attribute__((ext_vector_type(4))) short bf16x4;
typedef __attribute__((ext_vector_type(4))) float f32x4;
typedef unsigned short u16;
typedef unsigned int u32;

#define BN_EPS 1e-5f
#define NBINS 65536

__device__ __forceinline__ float b2f(u16 u) {
    u32 x = ((u32)u) << 16;
    float f; __builtin_memcpy(&f, &x, 4); return f;
}
__device__ __forceinline__ u16 f2b(float f) {
    f = fminf(fmaxf(f, -3.0e38f), 3.0e38f);
    __hip_bfloat16 h = __float2bfloat16(f);
    u16 s; __builtin_memcpy(&s, &h, 2); return s;
}
__device__ __forceinline__ bf16x8 cvt8(f32x4 a, f32x4 b) {
    bf16x8 r;
    r[0] = (short)f2b(a[0]); r[1] = (short)f2b(a[1]);
    r[2] = (short)f2b(a[2]); r[3] = (short)f2b(a[3]);
    r[4] = (short)f2b(b[0]); r[5] = (short)f2b(b[1]);
    r[6] = (short)f2b(b[2]); r[7] = (short)f2b(b[3]);
    return r;
}
#define MFMA(a, b, c) __builtin_amdgcn_mfma_f32_16x16x32_bf16((a), (b), (c), 0, 0, 0)

// 16x16x16 bf16 MFMA: A/B frag = 4 bf16 (k = quad*4 + j), C/D = f32x4
#if __has_builtin(__builtin_amdgcn_mfma_f32_16x16x16bf16_1k)
__device__ __forceinline__ f32x4 mfma16(bf16x4 a, bf16x4 b, f32x4 c) {
    return __builtin_amdgcn_mfma_f32_16x16x16bf16_1k(a, b, c, 0, 0, 0);
}
#else
__device__ __forceinline__ f32x4 mfma16(bf16x4 a, bf16x4 b, f32x4 c) {
    asm volatile("v_mfma_f32_16x16x16_bf16 %0, %1, %2, %0"
                 : "+v"(c) : "v"(a), "v"(b));
    return c;
}
#endif

// ---------------------------------------------------------------------------
// k_prep: ONE launch replacing 6 k_cvtw + hipMemsetAsync + host-side bias math.
// - converts all weights fp32->bf16 into the wb arena, PRE-SCALING by the BN
//   scale of the consuming layer (folds bn1 into Wnei/Wroot, bn2 into Wo,
//   bn3 into W2) -> k_hout needs ONE accumulator, k_mlp epilogue is an fma.
// - zeroes the CSR counts array.
// - computes fused per-col epilogue vectors: cb, xs (hout), cb3, xs3 (mlp).
// ---------------------------------------------------------------------------
__global__ __launch_bounds__(256) void k_prep(
    const float* __restrict__ Wroot, const float* __restrict__ Wnei,
    const float* __restrict__ Wqkv,  const float* __restrict__ Wo,
    const float* __restrict__ W1,    const float* __restrict__ W2,
    const float* __restrict__ bnei,  const float* __restrict__ bo,
    const float* __restrict__ b2,
    const float* __restrict__ g1, const float* __restrict__ be1,
    const float* __restrict__ m1, const float* __restrict__ v1,
    const float* __restrict__ g2, const float* __restrict__ be2,
    const float* __restrict__ m2, const float* __restrict__ v2,
    const float* __restrict__ g3, const float* __restrict__ be3,
    const float* __restrict__ m3, const float* __restrict__ v3,
    u16* __restrict__ wb, int* __restrict__ counts, float* __restrict__ fvec)
{
    const int i = blockIdx.x * 256 + threadIdx.x;
    if (i < 655360) {
        float v;
        if (i < 65536) {                       // Wroot * sc1
            const int col = i >> 8;
            v = Wroot[i] * (g1[col] * rsqrtf(v1[col] + BN_EPS));
        } else if (i < 131072) {               // Wnei * sc1
            const int j = i - 65536, col = j >> 8;
            v = Wnei[j] * (g1[col] * rsqrtf(v1[col] + BN_EPS));
        } else if (i < 327680) {               // Wqkv plain
            v = Wqkv[i - 131072];
        } else if (i < 393216) {               // Wo * sc2
            const int j = i - 327680, col = j >> 8;
            v = Wo[j] * (g2[col] * rsqrtf(v2[col] + BN_EPS));
        } else if (i < 524288) {               // W1 plain
            v = W1[i - 393216];
        } else {                               // W2 * sc3 (W2 is [256][512])
            const int j = i - 524288, col = j >> 9;
            v = W2[j] * (g3[col] * rsqrtf(v3[col] + BN_EPS));
        }
        wb[i] = f2b(v);
    } else if (i < 720896) {
        counts[i - 655360] = 0;
    } else if (i < 721152) {
        const int col = i - 720896;
        const float sc1 = g1[col] * rsqrtf(v1[col] + BN_EPS);
        const float sc2 = g2[col] * rsqrtf(v2[col] + BN_EPS);
        const float sc3 = g3[col] * rsqrtf(v3[col] + BN_EPS);
        fvec[col]       = sc1 * (bnei[col] - m1[col]) + be1[col]
                        + sc2 * (bo[col]  - m2[col]) + be2[col];   // cb
        fvec[256 + col] = sc1 + sc2;                               // xs
        fvec[512 + col] = sc3 * (b2[col] - m3[col]) + be3[col];    // cb3
        fvec[768 + col] = sc3;                                     // xs3
    }
}

__global__ __launch_bounds__(256) void k_cvtx(const float* __restrict__ src,
                                              u16* __restrict__ dst, int n4) {
    const int i = blockIdx.x * 256 + threadIdx.x;
    if (i < n4) {
        const f32x4 v = ((const f32x4*)src)[i];
        ushort4 pk;
        pk.x = f2b(v[0]); pk.y = f2b(v[1]); pk.z = f2b(v[2]); pk.w = f2b(v[3]);
        ((ushort4*)dst)[i] = pk;
    }
}

// ---------------------------------------------------------------------------
// CSR build: hist -> scan -> reorder (counting sort of edges by dst)
// ---------------------------------------------------------------------------
__global__ __launch_bounds__(256) void k_hist(
    const int* __restrict__ edst, int* __restrict__ counts, int E) {
    const int i = blockIdx.x * 256 + threadIdx.x;
    if (i < E) atomicAdd(&counts[edst[i]], 1);
}

__global__ __launch_bounds__(1024) void k_scan(
    const int* __restrict__ counts, int* __restrict__ start,
    int* __restrict__ cursor) {
    __shared__ int sums[1024];
    const int t = threadIdx.x;
    const int base = t * 64;
    int s = 0;
#pragma unroll 8
    for (int j = 0; j < 64; ++j) s += counts[base + j];
    sums[t] = s;
    __syncthreads();
    for (int off = 1; off < 1024; off <<= 1) {
        const int tmp = (t >= off) ? sums[t - off] : 0;
        __syncthreads();
        sums[t] += tmp;
        __syncthreads();
    }
    int run = sums[t] - s;
    for (int j = 0; j < 64; ++j) {
        start[base + j] = run;
        cursor[base + j] = run;
        run += counts[base + j];
    }
    if (t == 1023) start[NBINS] = run;
}

__global__ __launch_bounds__(256) void k_reorder(
    const int* __restrict__ esrc, const int* __restrict__ edst,
    int* __restrict__ cursor, int* __restrict__ ssrc, int E) {
    const int i = blockIdx.x * 256 + threadIdx.x;
    if (i < E) {
        const int p = atomicAdd(&cursor[edst[i]], 1);
        ssrc[p] = esrc[i];
    }
}

// One wave per dst row: register-accumulate (fp32) from bf16 x, bf16 row out.
__global__ __launch_bounds__(256) void k_aggregate(
    const u16* __restrict__ xb, const int* __restrict__ ssrc,
    const int* __restrict__ start, u16* __restrict__ agg,
    int lo, int hi) {
    const int rel = (blockIdx.x << 2) + (threadIdx.x >> 6);
    const int r = lo + rel;
    if (r >= hi) return;
    const int lane = threadIdx.x & 63;
    const int s0 = start[r], s1 = start[r + 1];
    f32x4 acc = {0.f, 0.f, 0.f, 0.f};
    int j = s0;
    int sNext = (j < s1) ? ssrc[j] : 0;
    while (j < s1) {
        const int s = sNext;
        ++j;
        if (j < s1) sNext = ssrc[j];
        const ushort4 xv = *(const ushort4*)(xb + (size_t)s * 256 + lane * 4);
        acc[0] += b2f(xv.x); acc[1] += b2f(xv.y);
        acc[2] += b2f(xv.z); acc[3] += b2f(xv.w);
    }
    ushort4 pk;
    pk.x = f2b(acc[0]); pk.y = f2b(acc[1]); pk.z = f2b(acc[2]); pk.w = f2b(acc[3]);
    *(ushort4*)(agg + (size_t)rel * 256 + lane * 4) = pk;
}

// ---------------------------------------------------------------------------
// MFMA GEMM core (bf16 A): acc += A[rows,K] @ W[Nout,K]^T, NT 16-col tiles.
// ---------------------------------------------------------------------------
template<int NT>
__device__ __forceinline__ void gemm_accN(const u16* A, int lda, int Mload,
                                          const u16* W, int K,
                                          int rowBase, int colBase,
                                          f32x4 (&acc)[2][NT])
{
    const int lane = threadIdx.x & 63;
    const int r16 = lane & 15;
    const int quad = lane >> 4;
    int r0 = rowBase + r16;
    int r1 = rowBase + 16 + r16;
    const bool z0 = (r0 >= Mload), z1 = (r1 >= Mload);
    if (z0) r0 = 0;
    if (z1) r1 = 0;
    const bf16x8 zf = {0,0,0,0,0,0,0,0};
    for (int kk = 0; kk < K; kk += 32) {
        const int ko = kk + quad * 8;
        bf16x8 a0 = *(const bf16x8*)(A + (size_t)r0 * lda + ko);
        bf16x8 a1 = *(const bf16x8*)(A + (size_t)r1 * lda + ko);
        if (z0) a0 = zf;
        if (z1) a1 = zf;
#pragma unroll
        for (int nt = 0; nt < NT; ++nt) {
            const bf16x8 b = *(const bf16x8*)(W + (size_t)(colBase + nt * 16 + r16) * K + ko);
            acc[0][nt] = MFMA(a0, b, acc[0][nt]);
            acc[1][nt] = MFMA(a1, b, acc[1][nt]);
        }
    }
}

// ---------------------------------------------------------------------------
// MFMA flash attention, one block per (graph, head), XCD-aware block remap.
// EXACT revert to the proven 169 us / 64-VGPR version (round-4 result):
// swapped-QK^T in-register softmax, __expf, inline mask, no reg hoisting.
// ---------------------------------------------------------------------------
__global__ __launch_bounds__(256) void k_attn(
    const u16* __restrict__ xb, const u16* __restrict__ Wqkv,
    const float* __restrict__ bqkv, u16* __restrict__ attnOut,
    int lo, int N, int ngraph)
{
    __shared__ u16 ks_s[256 * 40];   // K: [key][d], stride 40; q-scratch pre-K
    __shared__ u16 vt_s[32 * 264];   // V^T: [d][key], stride 264
    int brel, h;
    if ((ngraph & 7) == 0) {
        const int x8 = blockIdx.x & 7;      // XCD slot
        const int j  = blockIdx.x >> 3;
        h = j & 7;
        brel = x8 + 8 * (j >> 3);           // same-graph heads: same XCD
    } else {
        brel = blockIdx.x >> 3;
        h = blockIdx.x & 7;
    }
    const int base = lo + brel * 256;
    const int count = min(256, N - base);
    const int t = threadIdx.x;
    const int wave = t >> 6;
    const int lane = t & 63;
    const int r16 = lane & 15;
    const int quad = lane >> 4;
    u16* qsc = ks_s + wave * 64 * 40;       // q transpose scratch (own K slice)
    const float scale = 0.17677669529663687f;  // 1/sqrt(32)

    bf16x8 qa[4];   // B-frags (Q[q][d]) covering this wave's 64 query rows

    // ---- phase 1: projections ----
#pragma unroll
    for (int sel = 0; sel < 3; ++sel) {
        f32x4 acc[4][2] = {};
        for (int kk = 0; kk < 256; kk += 32) {
            const int ko = kk + quad * 8;
            bf16x8 a[4];
#pragma unroll
            for (int mt = 0; mt < 4; ++mt) {
                int row = base + wave * 64 + mt * 16 + r16;
                row = min(row, N - 1);   // clamped rows produce unused outputs
                a[mt] = *(const bf16x8*)(xb + (size_t)row * 256 + ko);
            }
#pragma unroll
            for (int nt = 0; nt < 2; ++nt) {
                const int wrow = sel * 256 + h * 32 + nt * 16 + r16;
                const bf16x8 b = *(const bf16x8*)(Wqkv + (size_t)wrow * 256 + ko);
#pragma unroll
                for (int mt = 0; mt < 4; ++mt)
                    acc[mt][nt] = MFMA(a[mt], b, acc[mt][nt]);
            }
        }
        if (sel == 0) {
            // q (pre-scaled) -> own ks_s slice, then frag readback (in-wave dep)
#pragma unroll
            for (int nt = 0; nt < 2; ++nt) {
                const float bias = bqkv[h * 32 + nt * 16 + r16];
#pragma unroll
                for (int mt = 0; mt < 4; ++mt)
#pragma unroll
                    for (int r = 0; r < 4; ++r)
                        qsc[(mt * 16 + quad * 4 + r) * 40 + nt * 16 + r16] =
                            f2b((acc[mt][nt][r] + bias) * scale);
            }
#pragma unroll
            for (int mt = 0; mt < 4; ++mt)
                qa[mt] = *(const bf16x8*)(qsc + (mt * 16 + r16) * 40 + quad * 8);
        } else if (sel == 1) {
#pragma unroll
            for (int nt = 0; nt < 2; ++nt) {
                const float bias = bqkv[256 + h * 32 + nt * 16 + r16];
#pragma unroll
                for (int mt = 0; mt < 4; ++mt)
#pragma unroll
                    for (int r = 0; r < 4; ++r) {
                        const int key = wave * 64 + mt * 16 + quad * 4 + r;
                        ks_s[key * 40 + nt * 16 + r16] = f2b(acc[mt][nt][r] + bias);
                    }
            }
        } else {
#pragma unroll
            for (int nt = 0; nt < 2; ++nt) {
                const int d = nt * 16 + r16;
                const float bias = bqkv[512 + h * 32 + d];
#pragma unroll
                for (int mt = 0; mt < 4; ++mt) {
                    const int key0 = wave * 64 + mt * 16 + quad * 4;
                    ushort4 pk;
                    pk.x = f2b(acc[mt][nt][0] + bias);
                    pk.y = f2b(acc[mt][nt][1] + bias);
                    pk.z = f2b(acc[mt][nt][2] + bias);
                    pk.w = f2b(acc[mt][nt][3] + bias);
                    *(ushort4*)(vt_s + d * 264 + key0) = pk;
                }
            }
        }
    }
    __syncthreads();

    // ---- phase 2: flash over key-blocks, softmax fully in-register ----
#pragma unroll
    for (int mp = 0; mp < 2; ++mp) {
        f32x4 O[2][2] = {};          // [mt][ntd]: D[q][d], q=quad*4+r, d=lane&15
        float rs2[2] = {0.f, 0.f};
        for (int kb = 0; kb < 8; ++kb) {
            bf16x8 bk[2];
#pragma unroll
            for (int kt = 0; kt < 2; ++kt)
                bk[kt] = *(const bf16x8*)(ks_s + (kb * 32 + kt * 16 + r16) * 40 + quad * 8);
            f32x4 st[2][2];
#pragma unroll
            for (int kt = 0; kt < 2; ++kt)
#pragma unroll
                for (int mt = 0; mt < 2; ++mt) {
                    const f32x4 z = {0.f, 0.f, 0.f, 0.f};
                    st[kt][mt] = MFMA(bk[kt], qa[mp * 2 + mt], z);
                }
            bf16x4 pf[2][2];
#pragma unroll
            for (int kt = 0; kt < 2; ++kt) {
                const int key0 = kb * 32 + kt * 16 + quad * 4;
#pragma unroll
                for (int mt = 0; mt < 2; ++mt) {
                    bf16x4 p;
#pragma unroll
                    for (int r = 0; r < 4; ++r) {
                        const float s = fminf(fmaxf(st[kt][mt][r], -60.f), 60.f);
                        const float e = (key0 + r < count) ? __expf(s) : 0.f;
                        rs2[mt] += e;
                        p[r] = (short)f2b(e);
                    }
                    pf[kt][mt] = p;
                }
            }
            bf16x4 bv[2][2];
#pragma unroll
            for (int kt = 0; kt < 2; ++kt)
#pragma unroll
                for (int ntd = 0; ntd < 2; ++ntd)
                    bv[kt][ntd] = *(const bf16x4*)(vt_s + (ntd * 16 + r16) * 264
                                                   + kb * 32 + kt * 16 + quad * 4);
#pragma unroll
            for (int kt = 0; kt < 2; ++kt)
#pragma unroll
                for (int mt = 0; mt < 2; ++mt)
#pragma unroll
                    for (int ntd = 0; ntd < 2; ++ntd)
                        O[mt][ntd] = mfma16(pf[kt][mt], bv[kt][ntd], O[mt][ntd]);
        }
#pragma unroll
        for (int mt = 0; mt < 2; ++mt) {
            float v = rs2[mt];
            v += __shfl_xor(v, 16, 64);
            v += __shfl_xor(v, 32, 64);
            rs2[mt] = v;
        }
#pragma unroll
        for (int mt = 0; mt < 2; ++mt) {
#pragma unroll
            for (int r = 0; r < 4; ++r) {
                const float rsv = __shfl(rs2[mt], quad * 4 + r, 16);
                const float inv = 1.f / fmaxf(rsv, 1e-30f);
                const int qrow = wave * 64 + mp * 32 + mt * 16 + quad * 4 + r;
#pragma unroll
                for (int ntd = 0; ntd < 2; ++ntd)
                    attnOut[(size_t)(brel * 256 + qrow) * 256 + h * 32 + ntd * 16 + r16]
                        = f2b(O[mt][ntd][r] * inv);
            }
        }
    }
}

// ---------------------------------------------------------------------------
// Fused epilogue with BN-prescaled weights (single accumulator):
//   dout = agg@(sc1 Wnei)^T + xb@(sc1 Wroot)^T + attn@(sc2 Wo)^T
//        + (sc1+sc2)*x + cb[col]
// 128-wide col tiles (grid.x = 2): A-panels read 2x instead of 4x.
// ---------------------------------------------------------------------------
__global__ __launch_bounds__(256) void k_hout(
    const u16* __restrict__ attn, const u16* __restrict__ agg,
    const u16* __restrict__ xbc, const float* __restrict__ x,
    const u16* __restrict__ Wo, const u16* __restrict__ Wnei,
    const u16* __restrict__ Wroot, const float* __restrict__ fvec,
    float* __restrict__ dout, int lo, int hi)
{
    const int wave = threadIdx.x >> 6;
    const int rowBase = blockIdx.y * 128 + wave * 32;
    const int colBase = blockIdx.x * 128;
    const int ML = hi - lo;
    f32x4 acc[2][8] = {};
    gemm_accN<8>(agg, 256, ML, Wnei, 256, rowBase, colBase, acc);
    gemm_accN<8>(xbc, 256, ML, Wroot, 256, rowBase, colBase, acc);
    gemm_accN<8>(attn, 256, ML, Wo, 256, rowBase, colBase, acc);
    const int lane = threadIdx.x & 63;
    const int r16 = lane & 15, quad = lane >> 4;
#pragma unroll
    for (int nt = 0; nt < 8; ++nt) {
        const int col = colBase + nt * 16 + r16;
        const float cb = fvec[col];
        const float xs = fvec[256 + col];
#pragma unroll
        for (int tt = 0; tt < 2; ++tt) {
#pragma unroll
            for (int r = 0; r < 4; ++r) {
                const int rel = rowBase + tt * 16 + quad * 4 + r;
                if (rel < ML) {
                    const size_t idx = (size_t)(lo + rel) * 256 + col;
                    dout[idx] = acc[tt][nt][r] + xs * x[idx] + cb;
                }
            }
        }
    }
}

// Fused MLP + bn3 (bn3 folded into W2 at prep), in place over d_out.
//   dout = relu(dout@W1^T + b1)@(sc3 W2)^T + xs3[col]*dout + cb3[col]
__global__ __launch_bounds__(256) void k_mlp(
    const u16* __restrict__ W1, const float* __restrict__ b1,
    const u16* __restrict__ W2, const float* __restrict__ fvec,
    float* __restrict__ dout, int N)
{
    __shared__ u16 as[64 * 264];   // A tile bf16 (64x256), stride 264
    __shared__ u16 ts[64 * 136];   // relu'd Y1 chunk (64x128), stride 136
    const int rowBase = blockIdx.x * 64;
    const int t = threadIdx.x;
    const int wave = t >> 6;
    const int lane = t & 63;
    const int r16 = lane & 15;
    const int quad = lane >> 4;

#pragma unroll
    for (int i = t; i < 64 * 64; i += 256) {
        const int row = i >> 6;
        const int c4 = i & 63;
        int grow = rowBase + row;
        grow = min(grow, N - 1);
        const f32x4 v = *(const f32x4*)(dout + (size_t)grow * 256 + c4 * 4);
        ushort4 pk;
        pk.x = f2b(v[0]); pk.y = f2b(v[1]); pk.z = f2b(v[2]); pk.w = f2b(v[3]);
        *(ushort4*)(as + row * 264 + c4 * 4) = pk;
    }
    __syncthreads();

    f32x4 yacc[4][4] = {};

    for (int s = 0; s < 4; ++s) {
        f32x4 a1[4][2] = {};
        for (int kk = 0; kk < 256; kk += 32) {
            const int ko = kk + quad * 8;
            bf16x8 a[4];
#pragma unroll
            for (int mt = 0; mt < 4; ++mt)
                a[mt] = *(const bf16x8*)(as + (mt * 16 + r16) * 264 + ko);
#pragma unroll
            for (int nt = 0; nt < 2; ++nt) {
                const int wrow = s * 128 + wave * 32 + nt * 16 + r16;
                const bf16x8 b = *(const bf16x8*)(W1 + (size_t)wrow * 256 + ko);
#pragma unroll
                for (int mt = 0; mt < 4; ++mt)
                    a1[mt][nt] = MFMA(a[mt], b, a1[mt][nt]);
            }
        }
        __syncthreads();
#pragma unroll
        for (int nt = 0; nt < 2; ++nt) {
            const int col = wave * 32 + nt * 16 + r16;
            const float bias = b1[s * 128 + col];
#pragma unroll
            for (int mt = 0; mt < 4; ++mt) {
#pragma unroll
                for (int r = 0; r < 4; ++r) {
                    const int row = mt * 16 + quad * 4 + r;
                    ts[row * 136 + col] = f2b(fmaxf(a1[mt][nt][r] + bias, 0.f));
                }
            }
        }
        __syncthreads();
        for (int kk = 0; kk < 128; kk += 32) {
            const int ko = kk + quad * 8;
            bf16x8 a[4];
#pragma unroll
            for (int mt = 0; mt < 4; ++mt)
                a[mt] = *(const bf16x8*)(ts + (mt * 16 + r16) * 136 + ko);
#pragma unroll
            for (int nt = 0; nt < 4; ++nt) {
                const int wrow = wave * 64 + nt * 16 + r16;
                const bf16x8 b = *(const bf16x8*)(W2 + (size_t)wrow * 512 + s * 128 + ko);
#pragma unroll
                for (int mt = 0; mt < 4; ++mt)
                    yacc[mt][nt] = MFMA(a[mt], b, yacc[mt][nt]);
            }
        }
    }
#pragma unroll
    for (int nt = 0; nt < 4; ++nt) {
        const int col = wave * 64 + nt * 16 + r16;
        const float cb3 = fvec[512 + col];
        const float xs3 = fvec[768 + col];
#pragma unroll
        for (int mt = 0; mt < 4; ++mt) {
#pragma unroll
            for (int r = 0; r < 4; ++r) {
                const int grow = rowBase + mt * 16 + quad * 4 + r;
                if (grow < N) {
                    const size_t idx = (size_t)grow * 256 + col;
                    dout[idx] = yacc[mt][nt][r] + xs3 * dout[idx] + cb3;
                }
            }
        }
    }
}

extern "C" void kernel_launch(void* const* d_in, const int* in_sizes, int n_in,
                              void* d_out, int out_size, void* d_ws, size_t ws_size,
                              hipStream_t stream)
{
    (void)n_in; (void)out_size;
    const int N = in_sizes[0] / 256;
    const int E = in_sizes[1] / 2;

    const float* x     = (const float*)d_in[0];
    const int*   ei    = (const int*)d_in[1];
    const float* Wroot = (const float*)d_in[3];
    const float* Wnei  = (const float*)d_in[4];
    const float* bnei  = (const float*)d_in[5];
    const float* Wqkv  = (const float*)d_in[6];
    const float* bqkv  = (const float*)d_in[7];
    const float* Wo    = (const float*)d_in[8];
    const float* bo    = (const float*)d_in[9];
    const float* W1    = (const float*)d_in[10];
    const float* b1    = (const float*)d_in[11];
    const float* W2    = (const float*)d_in[12];
    const float* b2    = (const float*)d_in[13];
    const float* g1 = (const float*)d_in[14], *be1 = (const float*)d_in[15];
    const float* m1 = (const float*)d_in[16], *v1  = (const float*)d_in[17];
    const float* g2 = (const float*)d_in[18], *be2 = (const float*)d_in[19];
    const float* m2 = (const float*)d_in[20], *v2  = (const float*)d_in[21];
    const float* g3 = (const float*)d_in[22], *be3 = (const float*)d_in[23];
    const float* m3 = (const float*)d_in[24], *v3  = (const float*)d_in[25];
    float* dout = (float*)d_out;

    // --- d_ws layout ---
    // [0, 2 MiB)   weight arena (bf16, BN-prescaled) + fvec (4x256 f32)
    // [2, 3 MiB)   CSR meta: counts | start | cursor
    // [3, 7 MiB)   sorted src indices
    // [7, 39 MiB)  xb: x as bf16
    // [39 MiB...)  chunk arena: agg | attn
    u16* wb = (u16*)d_ws;
    u16* Wroot_b = wb;
    u16* Wnei_b  = wb + 65536;
    u16* Wqkv_b  = wb + 131072;
    u16* Wo_b    = wb + 327680;
    u16* W1_b    = wb + 393216;
    u16* W2_b    = wb + 524288;
    float* fvec  = (float*)(wb + 655360);   // cb | xs | cb3 | xs3
    const size_t WB_BYTES   = 2u << 20;
    const size_t META_BYTES = 1u << 20;
    const size_t SORT_BYTES = 4u << 20;
    const size_t XB_BYTES   = 32u << 20;
    const size_t FIXED = WB_BYTES + META_BYTES + SORT_BYTES + XB_BYTES;  // 39 MiB

    int* meta   = (int*)((char*)d_ws + WB_BYTES);
    int* counts = meta;
    int* start  = meta + NBINS;
    int* cursor = start + NBINS + 1;
    int* ssrc   = (int*)((char*)d_ws + WB_BYTES + META_BYTES);
    u16* xb     = (u16*)((char*)d_ws + WB_BYTES + META_BYTES + SORT_BYTES);

    // One prep launch: all weight converts (+BN fold) + counts zero + fvec
    k_prep<<<dim3(2817), 256, 0, stream>>>(
        Wroot, Wnei, Wqkv, Wo, W1, W2, bnei, bo, b2,
        g1, be1, m1, v1, g2, be2, m2, v2, g3, be3, m3, v3,
        wb, counts, fvec);
    const int n4 = (N * 256) / 4;
    k_cvtx<<<dim3((n4 + 255) / 256), 256, 0, stream>>>(x, xb, n4);

    size_t arena = (ws_size > FIXED) ? (ws_size - FIXED) : 0;
    size_t maxRows = arena / 1024;     // TWO bf16 rows per node (agg + attn)
    int chunkRows = (int)((maxRows < 65536 ? maxRows : 65536) & ~(size_t)255);
    if (chunkRows < 256) chunkRows = 256;

    u16* agg  = (u16*)((char*)d_ws + FIXED);
    u16* attn = agg + (size_t)chunkRows * 256;

    // CSR build (counts already zeroed by k_prep)
    k_hist   <<<dim3((E + 255) / 256), 256, 0, stream>>>(ei + E, counts, E);
    k_scan   <<<dim3(1), 1024, 0, stream>>>(counts, start, cursor);
    k_reorder<<<dim3((E + 255) / 256), 256, 0, stream>>>(ei, ei + E, cursor, ssrc, E);

    // Per chunk: aggregate + attn, then fused h1+h2 epilogue into d_out
    for (int lo = 0; lo < N; lo += chunkRows) {
        const int hi = min(lo + chunkRows, N);
        const int ngraph = (hi - lo + 255) / 256;
        k_aggregate<<<dim3((hi - lo + 3) / 4), 256, 0, stream>>>(xb, ssrc, start, agg, lo, hi);
        k_attn<<<dim3(ngraph * 8), 256, 0, stream>>>(xb, Wqkv_b, bqkv, attn, lo, N, ngraph);
        k_hout<<<dim3(2, (hi - lo + 127) / 128), 256, 0, stream>>>(
            attn, agg, xb + (size_t)lo * 256, x,
            Wo_b, Wnei_b, Wroot_b, fvec, dout, lo, hi);
    }
    // Fused MLP + bn3 (scale pre-folded), in place
    k_mlp<<<dim3((N + 63) / 64), 256, 0, stream>>>(
        W1_b, b1, W2_b, fvec, dout, N);
}

// Round 9
// 790.424 us; speedup vs baseline: 1.0566x; 1.0566x over previous
//
#include <hip/hip_runtime.h>
#include <hip/hip_bf16.h>

typedef __attribute__((ext_vector_type(8))) short bf16x8;
typedef __attribute__((ext_vector_type(4))) short bf16x4;
typedef __attribute__((ext_vector_type(4))) float f32x4;
typedef unsigned short u16;
typedef unsigned int u32;

#define BN_EPS 1e-5f
#define NBINS 65536

__device__ __forceinline__ float b2f(u16 u) {
    u32 x = ((u32)u) << 16;
    float f; __builtin_memcpy(&f, &x, 4); return f;
}
__device__ __forceinline__ u16 f2b(float f) {
    f = fminf(fmaxf(f, -3.0e38f), 3.0e38f);
    __hip_bfloat16 h = __float2bfloat16(f);
    u16 s; __builtin_memcpy(&s, &h, 2); return s;
}
__device__ __forceinline__ bf16x8 cvt8(f32x4 a, f32x4 b) {
    bf16x8 r;
    r[0] = (short)f2b(a[0]); r[1] = (short)f2b(a[1]);
    r[2] = (short)f2b(a[2]); r[3] = (short)f2b(a[3]);
    r[4] = (short)f2b(b[0]); r[5] = (short)f2b(b[1]);
    r[6] = (short)f2b(b[2]); r[7] = (short)f2b(b[3]);
    return r;
}
#define MFMA(a, b, c) __builtin_amdgcn_mfma_f32_16x16x32_bf16((a), (b), (c), 0, 0, 0)

// 16x16x16 bf16 MFMA: A/B frag = 4 bf16 (k = quad*4 + j), C/D = f32x4
#if __has_builtin(__builtin_amdgcn_mfma_f32_16x16x16bf16_1k)
__device__ __forceinline__ f32x4 mfma16(bf16x4 a, bf16x4 b, f32x4 c) {
    return __builtin_amdgcn_mfma_f32_16x16x16bf16_1k(a, b, c, 0, 0, 0);
}
#else
__device__ __forceinline__ f32x4 mfma16(bf16x4 a, bf16x4 b, f32x4 c) {
    asm volatile("v_mfma_f32_16x16x16_bf16 %0, %1, %2, %0"
                 : "+v"(c) : "v"(a), "v"(b));
    return c;
}
#endif

// ---------------------------------------------------------------------------
// k_prep: ONE launch: all weight converts (+BN fold), counts zero, fvec.
// ---------------------------------------------------------------------------
__global__ __launch_bounds__(256) void k_prep(
    const float* __restrict__ Wroot, const float* __restrict__ Wnei,
    const float* __restrict__ Wqkv,  const float* __restrict__ Wo,
    const float* __restrict__ W1,    const float* __restrict__ W2,
    const float* __restrict__ bnei,  const float* __restrict__ bo,
    const float* __restrict__ b2,
    const float* __restrict__ g1, const float* __restrict__ be1,
    const float* __restrict__ m1, const float* __restrict__ v1,
    const float* __restrict__ g2, const float* __restrict__ be2,
    const float* __restrict__ m2, const float* __restrict__ v2,
    const float* __restrict__ g3, const float* __restrict__ be3,
    const float* __restrict__ m3, const float* __restrict__ v3,
    u16* __restrict__ wb, int* __restrict__ counts, float* __restrict__ fvec)
{
    const int i = blockIdx.x * 256 + threadIdx.x;
    if (i < 655360) {
        float v;
        if (i < 65536) {                       // Wroot * sc1
            const int col = i >> 8;
            v = Wroot[i] * (g1[col] * rsqrtf(v1[col] + BN_EPS));
        } else if (i < 131072) {               // Wnei * sc1
            const int j = i - 65536, col = j >> 8;
            v = Wnei[j] * (g1[col] * rsqrtf(v1[col] + BN_EPS));
        } else if (i < 327680) {               // Wqkv plain
            v = Wqkv[i - 131072];
        } else if (i < 393216) {               // Wo * sc2
            const int j = i - 327680, col = j >> 8;
            v = Wo[j] * (g2[col] * rsqrtf(v2[col] + BN_EPS));
        } else if (i < 524288) {               // W1 plain
            v = W1[i - 393216];
        } else {                               // W2 * sc3 (W2 is [256][512])
            const int j = i - 524288, col = j >> 9;
            v = W2[j] * (g3[col] * rsqrtf(v3[col] + BN_EPS));
        }
        wb[i] = f2b(v);
    } else if (i < 720896) {
        counts[i - 655360] = 0;
    } else if (i < 721152) {
        const int col = i - 720896;
        const float sc1 = g1[col] * rsqrtf(v1[col] + BN_EPS);
        const float sc2 = g2[col] * rsqrtf(v2[col] + BN_EPS);
        const float sc3 = g3[col] * rsqrtf(v3[col] + BN_EPS);
        fvec[col]       = sc1 * (bnei[col] - m1[col]) + be1[col]
                        + sc2 * (bo[col]  - m2[col]) + be2[col];   // cb
        fvec[256 + col] = sc1 + sc2;                               // xs
        fvec[512 + col] = sc3 * (b2[col] - m3[col]) + be3[col];    // cb3
        fvec[768 + col] = sc3;                                     // xs3
    }
}

__global__ __launch_bounds__(256) void k_cvtx(const float* __restrict__ src,
                                              u16* __restrict__ dst, int n4) {
    const int i = blockIdx.x * 256 + threadIdx.x;
    if (i < n4) {
        const f32x4 v = ((const f32x4*)src)[i];
        ushort4 pk;
        pk.x = f2b(v[0]); pk.y = f2b(v[1]); pk.z = f2b(v[2]); pk.w = f2b(v[3]);
        ((ushort4*)dst)[i] = pk;
    }
}

// ---------------------------------------------------------------------------
// CSR build: hist -> scan -> reorder (counting sort of edges by dst)
// ---------------------------------------------------------------------------
__global__ __launch_bounds__(256) void k_hist(
    const int* __restrict__ edst, int* __restrict__ counts, int E) {
    const int i = blockIdx.x * 256 + threadIdx.x;
    if (i < E) atomicAdd(&counts[edst[i]], 1);
}

__global__ __launch_bounds__(1024) void k_scan(
    const int* __restrict__ counts, int* __restrict__ start,
    int* __restrict__ cursor) {
    __shared__ int sums[1024];
    const int t = threadIdx.x;
    const int base = t * 64;
    int s = 0;
#pragma unroll 8
    for (int j = 0; j < 64; ++j) s += counts[base + j];
    sums[t] = s;
    __syncthreads();
    for (int off = 1; off < 1024; off <<= 1) {
        const int tmp = (t >= off) ? sums[t - off] : 0;
        __syncthreads();
        sums[t] += tmp;
        __syncthreads();
    }
    int run = sums[t] - s;
    for (int j = 0; j < 64; ++j) {
        start[base + j] = run;
        cursor[base + j] = run;
        run += counts[base + j];
    }
    if (t == 1023) start[NBINS] = run;
}

__global__ __launch_bounds__(256) void k_reorder(
    const int* __restrict__ esrc, const int* __restrict__ edst,
    int* __restrict__ cursor, int* __restrict__ ssrc, int E) {
    const int i = blockIdx.x * 256 + threadIdx.x;
    if (i < E) {
        const int p = atomicAdd(&cursor[edst[i]], 1);
        ssrc[p] = esrc[i];
    }
}

// One wave per dst row: register-accumulate (fp32) from bf16 x, bf16 row out.
__global__ __launch_bounds__(256) void k_aggregate(
    const u16* __restrict__ xb, const int* __restrict__ ssrc,
    const int* __restrict__ start, u16* __restrict__ agg,
    int lo, int hi) {
    const int rel = (blockIdx.x << 2) + (threadIdx.x >> 6);
    const int r = lo + rel;
    if (r >= hi) return;
    const int lane = threadIdx.x & 63;
    const int s0 = start[r], s1 = start[r + 1];
    f32x4 acc = {0.f, 0.f, 0.f, 0.f};
    int j = s0;
    int sNext = (j < s1) ? ssrc[j] : 0;
    while (j < s1) {
        const int s = sNext;
        ++j;
        if (j < s1) sNext = ssrc[j];
        const ushort4 xv = *(const ushort4*)(xb + (size_t)s * 256 + lane * 4);
        acc[0] += b2f(xv.x); acc[1] += b2f(xv.y);
        acc[2] += b2f(xv.z); acc[3] += b2f(xv.w);
    }
    ushort4 pk;
    pk.x = f2b(acc[0]); pk.y = f2b(acc[1]); pk.z = f2b(acc[2]); pk.w = f2b(acc[3]);
    *(ushort4*)(agg + (size_t)rel * 256 + lane * 4) = pk;
}

// ---------------------------------------------------------------------------
// Fully-unrolled MFMA GEMM (K=256 compile-time): acc += A @ W^T, 4 col tiles.
// Runtime-K loop couldn't unroll -> only ~6 loads in flight -> 13% HBM.
// #pragma unroll on a literal trip count lets the compiler hoist all 8
// K-steps' loads (2 A + 4 B each) and batch vmcnt waits.
// ---------------------------------------------------------------------------
__device__ __forceinline__ void gemm_u4(const u16* __restrict__ A, int Mload,
                                        const u16* __restrict__ W,
                                        int rowBase, int colBase,
                                        f32x4 (&acc)[2][4])
{
    const int lane = threadIdx.x & 63;
    const int r16 = lane & 15;
    const int quad = lane >> 4;
    int r0 = rowBase + r16;
    int r1 = rowBase + 16 + r16;
    const bool z0 = (r0 >= Mload), z1 = (r1 >= Mload);
    if (z0) r0 = 0;
    if (z1) r1 = 0;
    const bf16x8 zf = {0,0,0,0,0,0,0,0};
#pragma unroll
    for (int kk = 0; kk < 256; kk += 32) {
        const int ko = kk + quad * 8;
        bf16x8 a0 = *(const bf16x8*)(A + (size_t)r0 * 256 + ko);
        bf16x8 a1 = *(const bf16x8*)(A + (size_t)r1 * 256 + ko);
        if (z0) a0 = zf;
        if (z1) a1 = zf;
#pragma unroll
        for (int nt = 0; nt < 4; ++nt) {
            const bf16x8 b = *(const bf16x8*)(W + (size_t)(colBase + nt * 16 + r16) * 256 + ko);
            acc[0][nt] = MFMA(a0, b, acc[0][nt]);
            acc[1][nt] = MFMA(a1, b, acc[1][nt]);
        }
    }
}

// ---------------------------------------------------------------------------
// MFMA flash attention, one block per (graph, head), XCD-aware block remap.
// Proven 169 us / 64-VGPR version: swapped-QK^T in-register softmax, __expf.
// ---------------------------------------------------------------------------
__global__ __launch_bounds__(256) void k_attn(
    const u16* __restrict__ xb, const u16* __restrict__ Wqkv,
    const float* __restrict__ bqkv, u16* __restrict__ attnOut,
    int lo, int N, int ngraph)
{
    __shared__ u16 ks_s[256 * 40];   // K: [key][d], stride 40; q-scratch pre-K
    __shared__ u16 vt_s[32 * 264];   // V^T: [d][key], stride 264
    int brel, h;
    if ((ngraph & 7) == 0) {
        const int x8 = blockIdx.x & 7;      // XCD slot
        const int j  = blockIdx.x >> 3;
        h = j & 7;
        brel = x8 + 8 * (j >> 3);           // same-graph heads: same XCD
    } else {
        brel = blockIdx.x >> 3;
        h = blockIdx.x & 7;
    }
    const int base = lo + brel * 256;
    const int count = min(256, N - base);
    const int t = threadIdx.x;
    const int wave = t >> 6;
    const int lane = t & 63;
    const int r16 = lane & 15;
    const int quad = lane >> 4;
    u16* qsc = ks_s + wave * 64 * 40;       // q transpose scratch (own K slice)
    const float scale = 0.17677669529663687f;  // 1/sqrt(32)

    bf16x8 qa[4];   // B-frags (Q[q][d]) covering this wave's 64 query rows

    // ---- phase 1: projections ----
#pragma unroll
    for (int sel = 0; sel < 3; ++sel) {
        f32x4 acc[4][2] = {};
        for (int kk = 0; kk < 256; kk += 32) {
            const int ko = kk + quad * 8;
            bf16x8 a[4];
#pragma unroll
            for (int mt = 0; mt < 4; ++mt) {
                int row = base + wave * 64 + mt * 16 + r16;
                row = min(row, N - 1);   // clamped rows produce unused outputs
                a[mt] = *(const bf16x8*)(xb + (size_t)row * 256 + ko);
            }
#pragma unroll
            for (int nt = 0; nt < 2; ++nt) {
                const int wrow = sel * 256 + h * 32 + nt * 16 + r16;
                const bf16x8 b = *(const bf16x8*)(Wqkv + (size_t)wrow * 256 + ko);
#pragma unroll
                for (int mt = 0; mt < 4; ++mt)
                    acc[mt][nt] = MFMA(a[mt], b, acc[mt][nt]);
            }
        }
        if (sel == 0) {
            // q (pre-scaled) -> own ks_s slice, then frag readback (in-wave dep)
#pragma unroll
            for (int nt = 0; nt < 2; ++nt) {
                const float bias = bqkv[h * 32 + nt * 16 + r16];
#pragma unroll
                for (int mt = 0; mt < 4; ++mt)
#pragma unroll
                    for (int r = 0; r < 4; ++r)
                        qsc[(mt * 16 + quad * 4 + r) * 40 + nt * 16 + r16] =
                            f2b((acc[mt][nt][r] + bias) * scale);
            }
#pragma unroll
            for (int mt = 0; mt < 4; ++mt)
                qa[mt] = *(const bf16x8*)(qsc + (mt * 16 + r16) * 40 + quad * 8);
        } else if (sel == 1) {
#pragma unroll
            for (int nt = 0; nt < 2; ++nt) {
                const float bias = bqkv[256 + h * 32 + nt * 16 + r16];
#pragma unroll
                for (int mt = 0; mt < 4; ++mt)
#pragma unroll
                    for (int r = 0; r < 4; ++r) {
                        const int key = wave * 64 + mt * 16 + quad * 4 + r;
                        ks_s[key * 40 + nt * 16 + r16] = f2b(acc[mt][nt][r] + bias);
                    }
            }
        } else {
#pragma unroll
            for (int nt = 0; nt < 2; ++nt) {
                const int d = nt * 16 + r16;
                const float bias = bqkv[512 + h * 32 + d];
#pragma unroll
                for (int mt = 0; mt < 4; ++mt) {
                    const int key0 = wave * 64 + mt * 16 + quad * 4;
                    ushort4 pk;
                    pk.x = f2b(acc[mt][nt][0] + bias);
                    pk.y = f2b(acc[mt][nt][1] + bias);
                    pk.z = f2b(acc[mt][nt][2] + bias);
                    pk.w = f2b(acc[mt][nt][3] + bias);
                    *(ushort4*)(vt_s + d * 264 + key0) = pk;
                }
            }
        }
    }
    __syncthreads();

    // ---- phase 2: flash over key-blocks, softmax fully in-register ----
#pragma unroll
    for (int mp = 0; mp < 2; ++mp) {
        f32x4 O[2][2] = {};          // [mt][ntd]: D[q][d], q=quad*4+r, d=lane&15
        float rs2[2] = {0.f, 0.f};
        for (int kb = 0; kb < 8; ++kb) {
            bf16x8 bk[2];
#pragma unroll
            for (int kt = 0; kt < 2; ++kt)
                bk[kt] = *(const bf16x8*)(ks_s + (kb * 32 + kt * 16 + r16) * 40 + quad * 8);
            f32x4 st[2][2];
#pragma unroll
            for (int kt = 0; kt < 2; ++kt)
#pragma unroll
                for (int mt = 0; mt < 2; ++mt) {
                    const f32x4 z = {0.f, 0.f, 0.f, 0.f};
                    st[kt][mt] = MFMA(bk[kt], qa[mp * 2 + mt], z);
                }
            bf16x4 pf[2][2];
#pragma unroll
            for (int kt = 0; kt < 2; ++kt) {
                const int key0 = kb * 32 + kt * 16 + quad * 4;
#pragma unroll
                for (int mt = 0; mt < 2; ++mt) {
                    bf16x4 p;
#pragma unroll
                    for (int r = 0; r < 4; ++r) {
                        const float s = fminf(fmaxf(st[kt][mt][r], -60.f), 60.f);
                        const float e = (key0 + r < count) ? __expf(s) : 0.f;
                        rs2[mt] += e;
                        p[r] = (short)f2b(e);
                    }
                    pf[kt][mt] = p;
                }
            }
            bf16x4 bv[2][2];
#pragma unroll
            for (int kt = 0; kt < 2; ++kt)
#pragma unroll
                for (int ntd = 0; ntd < 2; ++ntd)
                    bv[kt][ntd] = *(const bf16x4*)(vt_s + (ntd * 16 + r16) * 264
                                                   + kb * 32 + kt * 16 + quad * 4);
#pragma unroll
            for (int kt = 0; kt < 2; ++kt)
#pragma unroll
                for (int mt = 0; mt < 2; ++mt)
#pragma unroll
                    for (int ntd = 0; ntd < 2; ++ntd)
                        O[mt][ntd] = mfma16(pf[kt][mt], bv[kt][ntd], O[mt][ntd]);
        }
#pragma unroll
        for (int mt = 0; mt < 2; ++mt) {
            float v = rs2[mt];
            v += __shfl_xor(v, 16, 64);
            v += __shfl_xor(v, 32, 64);
            rs2[mt] = v;
        }
#pragma unroll
        for (int mt = 0; mt < 2; ++mt) {
#pragma unroll
            for (int r = 0; r < 4; ++r) {
                const float rsv = __shfl(rs2[mt], quad * 4 + r, 16);
                const float inv = 1.f / fmaxf(rsv, 1e-30f);
                const int qrow = wave * 64 + mp * 32 + mt * 16 + quad * 4 + r;
#pragma unroll
                for (int ntd = 0; ntd < 2; ++ntd)
                    attnOut[(size_t)(brel * 256 + qrow) * 256 + h * 32 + ntd * 16 + r16]
                        = f2b(O[mt][ntd][r] * inv);
            }
        }
    }
}

// ---------------------------------------------------------------------------
// Fused epilogue with BN-prescaled weights (single accumulator):
//   dout = agg@(sc1 Wnei)^T + xb@(sc1 Wroot)^T + attn@(sc2 Wo)^T
//        + (sc1+sc2)*x + cb[col]
// NT=4 / grid.x=4 (2048 blocks = 8/CU) + fully-unrolled K loops.
// ---------------------------------------------------------------------------
__global__ __launch_bounds__(256) void k_hout(
    const u16* __restrict__ attn, const u16* __restrict__ agg,
    const u16* __restrict__ xbc, const float* __restrict__ x,
    const u16* __restrict__ Wo, const u16* __restrict__ Wnei,
    const u16* __restrict__ Wroot, const float* __restrict__ fvec,
    float* __restrict__ dout, int lo, int hi)
{
    const int wave = threadIdx.x >> 6;
    const int rowBase = blockIdx.y * 128 + wave * 32;
    const int colBase = blockIdx.x * 64;
    const int ML = hi - lo;
    f32x4 acc[2][4] = {};
    gemm_u4(agg, ML, Wnei, rowBase, colBase, acc);
    gemm_u4(xbc, ML, Wroot, rowBase, colBase, acc);
    gemm_u4(attn, ML, Wo, rowBase, colBase, acc);
    const int lane = threadIdx.x & 63;
    const int r16 = lane & 15, quad = lane >> 4;
#pragma unroll
    for (int nt = 0; nt < 4; ++nt) {
        const int col = colBase + nt * 16 + r16;
        const float cb = fvec[col];
        const float xs = fvec[256 + col];
#pragma unroll
        for (int tt = 0; tt < 2; ++tt) {
#pragma unroll
            for (int r = 0; r < 4; ++r) {
                const int rel = rowBase + tt * 16 + quad * 4 + r;
                if (rel < ML) {
                    const size_t idx = (size_t)(lo + rel) * 256 + col;
                    dout[idx] = acc[tt][nt][r] + xs * x[idx] + cb;
                }
            }
        }
    }
}

// Fused MLP + bn3 (bn3 folded into W2 at prep), in place over d_out.
__global__ __launch_bounds__(256) void k_mlp(
    const u16* __restrict__ W1, const float* __restrict__ b1,
    const u16* __restrict__ W2, const float* __restrict__ fvec,
    float* __restrict__ dout, int N)
{
    __shared__ u16 as[64 * 264];   // A tile bf16 (64x256), stride 264
    __shared__ u16 ts[64 * 136];   // relu'd Y1 chunk (64x128), stride 136
    const int rowBase = blockIdx.x * 64;
    const int t = threadIdx.x;
    const int wave = t >> 6;
    const int lane = t & 63;
    const int r16 = lane & 15;
    const int quad = lane >> 4;

#pragma unroll
    for (int i = t; i < 64 * 64; i += 256) {
        const int row = i >> 6;
        const int c4 = i & 63;
        int grow = rowBase + row;
        grow = min(grow, N - 1);
        const f32x4 v = *(const f32x4*)(dout + (size_t)grow * 256 + c4 * 4);
        ushort4 pk;
        pk.x = f2b(v[0]); pk.y = f2b(v[1]); pk.z = f2b(v[2]); pk.w = f2b(v[3]);
        *(ushort4*)(as + row * 264 + c4 * 4) = pk;
    }
    __syncthreads();

    f32x4 yacc[4][4] = {};

    for (int s = 0; s < 4; ++s) {
        f32x4 a1[4][2] = {};
#pragma unroll
        for (int kk = 0; kk < 256; kk += 32) {
            const int ko = kk + quad * 8;
            bf16x8 a[4];
#pragma unroll
            for (int mt = 0; mt < 4; ++mt)
                a[mt] = *(const bf16x8*)(as + (mt * 16 + r16) * 264 + ko);
#pragma unroll
            for (int nt = 0; nt < 2; ++nt) {
                const int wrow = s * 128 + wave * 32 + nt * 16 + r16;
                const bf16x8 b = *(const bf16x8*)(W1 + (size_t)wrow * 256 + ko);
#pragma unroll
                for (int mt = 0; mt < 4; ++mt)
                    a1[mt][nt] = MFMA(a[mt], b, a1[mt][nt]);
            }
        }
        __syncthreads();
#pragma unroll
        for (int nt = 0; nt < 2; ++nt) {
            const int col = wave * 32 + nt * 16 + r16;
            const float bias = b1[s * 128 + col];
#pragma unroll
            for (int mt = 0; mt < 4; ++mt) {
#pragma unroll
                for (int r = 0; r < 4; ++r) {
                    const int row = mt * 16 + quad * 4 + r;
                    ts[row * 136 + col] = f2b(fmaxf(a1[mt][nt][r] + bias, 0.f));
                }
            }
        }
        __syncthreads();
#pragma unroll
        for (int kk = 0; kk < 128; kk += 32) {
            const int ko = kk + quad * 8;
            bf16x8 a[4];
#pragma unroll
            for (int mt = 0; mt < 4; ++mt)
                a[mt] = *(const bf16x8*)(ts + (mt * 16 + r16) * 136 + ko);
#pragma unroll
            for (int nt = 0; nt < 4; ++nt) {
                const int wrow = wave * 64 + nt * 16 + r16;
                const bf16x8 b = *(const bf16x8*)(W2 + (size_t)wrow * 512 + s * 128 + ko);
#pragma unroll
                for (int mt = 0; mt < 4; ++mt)
                    yacc[mt][nt] = MFMA(a[mt], b, yacc[mt][nt]);
            }
        }
    }
#pragma unroll
    for (int nt = 0; nt < 4; ++nt) {
        const int col = wave * 64 + nt * 16 + r16;
        const float cb3 = fvec[512 + col];
        const float xs3 = fvec[768 + col];
#pragma unroll
        for (int mt = 0; mt < 4; ++mt) {
#pragma unroll
            for (int r = 0; r < 4; ++r) {
                const int grow = rowBase + mt * 16 + quad * 4 + r;
                if (grow < N) {
                    const size_t idx = (size_t)grow * 256 + col;
                    dout[idx] = yacc[mt][nt][r] + xs3 * dout[idx] + cb3;
                }
            }
        }
    }
}

extern "C" void kernel_launch(void* const* d_in, const int* in_sizes, int n_in,
                              void* d_out, int out_size, void* d_ws, size_t ws_size,
                              hipStream_t stream)
{
    (void)n_in; (void)out_size;
    const int N = in_sizes[0] / 256;
    const int E = in_sizes[1] / 2;

    const float* x     = (const float*)d_in[0];
    const int*   ei    = (const int*)d_in[1];
    const float* Wroot = (const float*)d_in[3];
    const float* Wnei  = (const float*)d_in[4];
    const float* bnei  = (const float*)d_in[5];
    const float* Wqkv  = (const float*)d_in[6];
    const float* bqkv  = (const float*)d_in[7];
    const float* Wo    = (const float*)d_in[8];
    const float* bo    = (const float*)d_in[9];
    const float* W1    = (const float*)d_in[10];
    const float* b1    = (const float*)d_in[11];
    const float* W2    = (const float*)d_in[12];
    const float* b2    = (const float*)d_in[13];
    const float* g1 = (const float*)d_in[14], *be1 = (const float*)d_in[15];
    const float* m1 = (const float*)d_in[16], *v1  = (const float*)d_in[17];
    const float* g2 = (const float*)d_in[18], *be2 = (const float*)d_in[19];
    const float* m2 = (const float*)d_in[20], *v2  = (const float*)d_in[21];
    const float* g3 = (const float*)d_in[22], *be3 = (const float*)d_in[23];
    const float* m3 = (const float*)d_in[24], *v3  = (const float*)d_in[25];
    float* dout = (float*)d_out;

    u16* wb = (u16*)d_ws;
    u16* Wroot_b = wb;
    u16* Wnei_b  = wb + 65536;
    u16* Wqkv_b  = wb + 131072;
    u16* Wo_b    = wb + 327680;
    u16* W1_b    = wb + 393216;
    u16* W2_b    = wb + 524288;
    float* fvec  = (float*)(wb + 655360);   // cb | xs | cb3 | xs3
    const size_t WB_BYTES   = 2u << 20;
    const size_t META_BYTES = 1u << 20;
    const size_t SORT_BYTES = 4u << 20;
    const size_t XB_BYTES   = 32u << 20;
    const size_t FIXED = WB_BYTES + META_BYTES + SORT_BYTES + XB_BYTES;  // 39 MiB

    int* meta   = (int*)((char*)d_ws + WB_BYTES);
    int* counts = meta;
    int* start  = meta + NBINS;
    int* cursor = start + NBINS + 1;
    int* ssrc   = (int*)((char*)d_ws + WB_BYTES + META_BYTES);
    u16* xb     = (u16*)((char*)d_ws + WB_BYTES + META_BYTES + SORT_BYTES);

    k_prep<<<dim3(2817), 256, 0, stream>>>(
        Wroot, Wnei, Wqkv, Wo, W1, W2, bnei, bo, b2,
        g1, be1, m1, v1, g2, be2, m2, v2, g3, be3, m3, v3,
        wb, counts, fvec);
    const int n4 = (N * 256) / 4;
    k_cvtx<<<dim3((n4 + 255) / 256), 256, 0, stream>>>(x, xb, n4);

    size_t arena = (ws_size > FIXED) ? (ws_size - FIXED) : 0;
    size_t maxRows = arena / 1024;     // TWO bf16 rows per node (agg + attn)
    int chunkRows = (int)((maxRows < 65536 ? maxRows : 65536) & ~(size_t)255);
    if (chunkRows < 256) chunkRows = 256;

    u16* agg  = (u16*)((char*)d_ws + FIXED);
    u16* attn = agg + (size_t)chunkRows * 256;

    // CSR build (counts already zeroed by k_prep)
    k_hist   <<<dim3((E + 255) / 256), 256, 0, stream>>>(ei + E, counts, E);
    k_scan   <<<dim3(1), 1024, 0, stream>>>(counts, start, cursor);
    k_reorder<<<dim3((E + 255) / 256), 256, 0, stream>>>(ei, ei + E, cursor, ssrc, E);

    // Per chunk: aggregate + attn, then fused h1+h2 epilogue into d_out
    for (int lo = 0; lo < N; lo += chunkRows) {
        const int hi = min(lo + chunkRows, N);
        const int ngraph = (hi - lo + 255) / 256;
        k_aggregate<<<dim3((hi - lo + 3) / 4), 256, 0, stream>>>(xb, ssrc, start, agg, lo, hi);
        k_attn<<<dim3(ngraph * 8), 256, 0, stream>>>(xb, Wqkv_b, bqkv, attn, lo, N, ngraph);
        k_hout<<<dim3(4, (hi - lo + 127) / 128), 256, 0, stream>>>(
            attn, agg, xb + (size_t)lo * 256, x,
            Wo_b, Wnei_b, Wroot_b, fvec, dout, lo, hi);
    }
    // Fused MLP + bn3 (scale pre-folded), in place
    k_mlp<<<dim3((N + 63) / 64), 256, 0, stream>>>(
        W1_b, b1, W2_b, fvec, dout, N);
}